// Round 2
// baseline (151.371 us; speedup 1.0000x reference)
//
#include <hip/hip_runtime.h>
#include <hip/hip_bf16.h>
#include <math.h>

#define NB 4
#define LQ 768
#define NH 8
#define NE 64
#define ND 192   // 3*E augmented feature dim
#define TEMP 0.125f

typedef __attribute__((ext_vector_type(8))) __bf16 bf16x8;
typedef __attribute__((ext_vector_type(4))) float f32x4;

// ---------------- prep: build augmented double-bf16 (hi/lo) Q' and K' ----------------
// Q'[nh][l][0:64]   = Q * a * cos(w*l + off)     a = (1-gate)*softplus(gains)^2
// Q'[nh][l][64:128] = Q * a * sin(w*l + off)     w = 2*pi*sigmoid(freqs)/2
// Q'[nh][l][128:192]= Q * gate
// K'[nh][s][0:64]   = K * cos(w*s); [64:128] = K*sin(w*s); [128:192] = K
// Each plane stored twice: hi = bf16(x), lo = bf16(x - hi)  (double-bf16)
__global__ __launch_bounds__(256) void sinattn_prep(
    const float* __restrict__ Q, const float* __restrict__ K,
    const float* __restrict__ freqs, const float* __restrict__ offsets,
    const float* __restrict__ gains, const float* __restrict__ gate,
    __hip_bfloat16* __restrict__ Qhi, __hip_bfloat16* __restrict__ Qlo,
    __hip_bfloat16* __restrict__ Khi, __hip_bfloat16* __restrict__ Klo)
{
    int idx = blockIdx.x * 256 + threadIdx.x;       // ((n*L + l)*H + h)*E + e
    if (idx >= NB * LQ * NH * NE) return;
    int e = idx & 63;
    int h = (idx >> 6) & 7;
    int t = idx >> 9;
    int l = t % LQ;
    int n = t / LQ;
    int he = (h << 6) | e;

    float fr = freqs[he];
    float f  = 0.5f / (1.0f + expf(-fr));           // sigmoid(fr)/2
    float w  = 6.283185307179586f * f;
    float off = offsets[he];
    float gn  = gains[he];
    float g   = (gn > 20.0f) ? gn : log1pf(expf(gn)); // softplus
    float gt  = gate[he];
    float a   = (1.0f - gt) * g * g;

    float pk = w * (float)l;
    float pq = pk + off;
    float sq, cq, sk, ck;
    sincosf(pq, &sq, &cq);
    sincosf(pk, &sk, &ck);

    float q = Q[idx], k = K[idx];
    int nh = (n << 3) | h;
    int base = (nh * LQ + l) * ND;

    float qv[3] = { q * a * cq, q * a * sq, q * gt };
    float kv[3] = { k * ck,     k * sk,     k      };
    #pragma unroll
    for (int p = 0; p < 3; ++p) {
        __hip_bfloat16 qh = __float2bfloat16(qv[p]);
        __hip_bfloat16 kh = __float2bfloat16(kv[p]);
        Qhi[base + p * NE + e] = qh;
        Qlo[base + p * NE + e] = __float2bfloat16(qv[p] - __bfloat162float(qh));
        Khi[base + p * NE + e] = kh;
        Klo[base + p * NE + e] = __float2bfloat16(kv[p] - __bfloat162float(kh));
    }
}

// ---------------- flash attention, double-bf16 QK^T, bf16 PV ----------------
// grid: 32 (n*h) x 12 (Q tiles of 64). block = 256 (4 waves, 16 q-rows/wave).
__global__ __launch_bounds__(256, 2) void sinattn_flash(
    const __hip_bfloat16* __restrict__ Qhi, const __hip_bfloat16* __restrict__ Qlo,
    const __hip_bfloat16* __restrict__ Khi, const __hip_bfloat16* __restrict__ Klo,
    const float* __restrict__ V, const float* __restrict__ mask,
    const float* __restrict__ keylen, float* __restrict__ out)
{
    // pads: row strides chosen for 16B alignment + 2-way (free) bank aliasing
    __shared__ __attribute__((aligned(16))) __hip_bfloat16 sKhi[64 * 200];
    __shared__ __attribute__((aligned(16))) __hip_bfloat16 sKlo[64 * 200];
    __shared__ __attribute__((aligned(16))) __hip_bfloat16 sVt[64 * 88];  // [e][s]
    __shared__ __attribute__((aligned(16))) __hip_bfloat16 sP[4][16 * 72];

    int tid  = threadIdx.x;
    int wv   = tid >> 6;
    int lane = tid & 63;
    int grp  = lane >> 4;   // quad
    int r16  = lane & 15;

    int bid = blockIdx.x;
    int lt  = bid % 12;
    int nh  = bid / 12;
    int n   = nh >> 3;
    int h   = nh & 7;
    int l0  = lt * 64;

    // Q fragments (A-layout: row = lane&15, k = d0*32 + grp*8 + j) straight
    // from global into registers, reused across all 12 K-chunks.
    bf16x8 qhi[6], qlo[6];
    {
        size_t rbase = (size_t)(nh * LQ + l0 + wv * 16 + r16) * ND + grp * 8;
        #pragma unroll
        for (int d0 = 0; d0 < 6; ++d0) {
            qhi[d0] = *(const bf16x8*)(Qhi + rbase + d0 * 32);
            qlo[d0] = *(const bf16x8*)(Qlo + rbase + d0 * 32);
        }
    }

    float m_i[4], l_i[4];
    f32x4 O[4];
    #pragma unroll
    for (int rr = 0; rr < 4; ++rr) { m_i[rr] = -INFINITY; l_i[rr] = 0.f; }
    #pragma unroll
    for (int tt = 0; tt < 4; ++tt)
        #pragma unroll
        for (int rr = 0; rr < 4; ++rr) O[tt][rr] = 0.f;

    for (int c = 0; c < 12; ++c) {
        int s0 = c * 64;
        __syncthreads();   // prior chunk's reads of sK/sVt done

        // stage K chunk (hi + lo planes)
        {
            const __hip_bfloat16* Kh = Khi + (size_t)(nh * LQ + s0) * ND;
            const __hip_bfloat16* Kl = Klo + (size_t)(nh * LQ + s0) * ND;
            #pragma unroll
            for (int i = 0; i < 6; ++i) {
                int cj  = tid + 256 * i;
                int row = cj / 24;
                int cc  = cj - row * 24;
                *(uint4*)&sKhi[row * 200 + cc * 8] = *(const uint4*)(Kh + row * ND + cc * 8);
                *(uint4*)&sKlo[row * 200 + cc * 8] = *(const uint4*)(Kl + row * ND + cc * 8);
            }
        }
        // stage V chunk transposed: sVt[e][s_local]
        {
            int srow = tid >> 2;
            int e0   = (tid & 3) << 4;
            const float4* Vp = (const float4*)(V + ((size_t)(n * LQ + s0 + srow) * NH + h) * NE + e0);
            float4 a0 = Vp[0], a1 = Vp[1], a2 = Vp[2], a3 = Vp[3];
            float vv[16] = { a0.x,a0.y,a0.z,a0.w, a1.x,a1.y,a1.z,a1.w,
                             a2.x,a2.y,a2.z,a2.w, a3.x,a3.y,a3.z,a3.w };
            #pragma unroll
            for (int j = 0; j < 16; ++j)
                sVt[(e0 + j) * 88 + srow] = __float2bfloat16(vv[j]);
        }
        __syncthreads();

        // S = Q'.K'^T double-bf16: hi*hi + lo*hi + hi*lo (lo*lo negligible)
        f32x4 st[4];
        #pragma unroll
        for (int j = 0; j < 4; ++j)
            #pragma unroll
            for (int rr = 0; rr < 4; ++rr) st[j][rr] = 0.f;
        #pragma unroll
        for (int d0 = 0; d0 < 6; ++d0) {
            #pragma unroll
            for (int j = 0; j < 4; ++j) {
                bf16x8 bhi = *(const bf16x8*)&sKhi[(j * 16 + r16) * 200 + d0 * 32 + grp * 8];
                bf16x8 blo = *(const bf16x8*)&sKlo[(j * 16 + r16) * 200 + d0 * 32 + grp * 8];
                st[j] = __builtin_amdgcn_mfma_f32_16x16x32_bf16(qhi[d0], bhi, st[j], 0, 0, 0);
                st[j] = __builtin_amdgcn_mfma_f32_16x16x32_bf16(qlo[d0], bhi, st[j], 0, 0, 0);
                st[j] = __builtin_amdgcn_mfma_f32_16x16x32_bf16(qhi[d0], blo, st[j], 0, 0, 0);
            }
        }

        // online softmax (C layout: col=lane&15 (+16j), row=grp*4+rr)
        float kl[4];
        #pragma unroll
        for (int j = 0; j < 4; ++j) kl[j] = keylen[n * LQ + s0 + j * 16 + r16];
        #pragma unroll
        for (int rr = 0; rr < 4; ++rr) {
            int lrow = l0 + wv * 16 + grp * 4 + rr;
            float lg[4];
            float mx = -INFINITY;
            #pragma unroll
            for (int j = 0; j < 4; ++j) {
                int s = s0 + j * 16 + r16;
                lg[j] = TEMP * (st[j][rr] + mask[lrow * LQ + s] + kl[j]);
                mx = fmaxf(mx, lg[j]);
            }
            #pragma unroll
            for (int d = 1; d < 16; d <<= 1) mx = fmaxf(mx, __shfl_xor(mx, d));
            float mnew  = fmaxf(m_i[rr], mx);
            float alpha = __expf(m_i[rr] - mnew);   // exp(-inf)=0 on first chunk
            float rs = 0.f;
            #pragma unroll
            for (int j = 0; j < 4; ++j) {
                float p = __expf(lg[j] - mnew);
                rs += p;
                sP[wv][(grp * 4 + rr) * 72 + j * 16 + r16] = __float2bfloat16(p);
            }
            #pragma unroll
            for (int d = 1; d < 16; d <<= 1) rs += __shfl_xor(rs, d);
            l_i[rr] = l_i[rr] * alpha + rs;
            m_i[rr] = mnew;
            #pragma unroll
            for (int tt = 0; tt < 4; ++tt) O[tt][rr] *= alpha;
        }
        __syncthreads();   // sP visible (C-layout -> A-layout round trip)

        // O += P.V  (A = P rows lane&15; B = sVt rows = e)
        #pragma unroll
        for (int kk = 0; kk < 2; ++kk) {
            bf16x8 pa = *(const bf16x8*)&sP[wv][r16 * 72 + kk * 32 + grp * 8];
            #pragma unroll
            for (int tt = 0; tt < 4; ++tt) {
                bf16x8 vb = *(const bf16x8*)&sVt[(tt * 16 + r16) * 88 + kk * 32 + grp * 8];
                O[tt] = __builtin_amdgcn_mfma_f32_16x16x32_bf16(pa, vb, O[tt], 0, 0, 0);
            }
        }
    }

    // epilogue: normalize and write out[n][l][h][e]
    #pragma unroll
    for (int rr = 0; rr < 4; ++rr) {
        float inv = 1.0f / l_i[rr];
        int lrow = l0 + wv * 16 + grp * 4 + rr;
        float* op = out + ((size_t)(n * LQ + lrow) * NH + h) * NE;
        #pragma unroll
        for (int tt = 0; tt < 4; ++tt)
            op[tt * 16 + r16] = O[tt][rr] * inv;
    }
}

extern "C" void kernel_launch(void* const* d_in, const int* in_sizes, int n_in,
                              void* d_out, int out_size, void* d_ws, size_t ws_size,
                              hipStream_t stream)
{
    const float* Q      = (const float*)d_in[0];
    const float* K      = (const float*)d_in[1];
    const float* V      = (const float*)d_in[2];
    const float* mask   = (const float*)d_in[3];
    const float* keylen = (const float*)d_in[4];
    const float* freqs  = (const float*)d_in[5];
    const float* offs   = (const float*)d_in[6];
    const float* gains  = (const float*)d_in[7];
    const float* gate   = (const float*)d_in[8];
    float* out = (float*)d_out;

    const size_t P = (size_t)NB * NH * LQ * ND;   // 4.72M elems / plane (9.44 MB)
    __hip_bfloat16* Qhi = (__hip_bfloat16*)d_ws;
    __hip_bfloat16* Qlo = Qhi + P;
    __hip_bfloat16* Khi = Qlo + P;
    __hip_bfloat16* Klo = Khi + P;

    sinattn_prep<<<6144, 256, 0, stream>>>(Q, K, freqs, offs, gains, gate,
                                           Qhi, Qlo, Khi, Klo);
    sinattn_flash<<<NB * NH * (LQ / 64), 256, 0, stream>>>(Qhi, Qlo, Khi, Klo,
                                                           V, mask, keylen, out);
}